// Round 4
// baseline (449.191 us; speedup 1.0000x reference)
//
#include <hip/hip_runtime.h>

// UpsampleUpFIRDn (up=2, 4x4 FIR). Wave-per-input-row formulation:
// lane t holds float4 of input cols 4t..4t+3 for rows ty-1, ty, ty+1;
// produces output rows 2ty, 2ty+1, cols 8t..8t+7. Halos via __shfl.
//
// Weight map (validated round 1): for output (oy,ox), taps are input
// (r0,r1)x(c0,c1) with r0=(oy-1)>>1 etc.;
//   oy even: row weights k[3][*] (top tap), k[1][*] (bottom)
//   oy odd : k[2][*], k[0][*]
//   ox even: col weights k[*][3] (left tap), k[*][1] (right)
//   ox odd : k[*][2], k[*][0]

typedef float v2f __attribute__((ext_vector_type(2)));

__device__ __forceinline__ void store8(float* b, const float v[8], int mis, int tail)
{
    // b points at float index that is even iff !mis. tail: lane 63 (ox=511 invalid).
    if (!mis) {
        v2f* b2 = (v2f*)b;
        __builtin_nontemporal_store((v2f){v[0], v[1]}, b2);
        __builtin_nontemporal_store((v2f){v[2], v[3]}, b2 + 1);
        __builtin_nontemporal_store((v2f){v[4], v[5]}, b2 + 2);
        if (!tail) __builtin_nontemporal_store((v2f){v[6], v[7]}, b2 + 3);
        else       __builtin_nontemporal_store(v[6], b + 6);
    } else {
        __builtin_nontemporal_store(v[0], b);
        v2f* b2 = (v2f*)(b + 1);
        __builtin_nontemporal_store((v2f){v[1], v[2]}, b2);
        __builtin_nontemporal_store((v2f){v[3], v[4]}, b2 + 1);
        __builtin_nontemporal_store((v2f){v[5], v[6]}, b2 + 2);
        if (!tail) __builtin_nontemporal_store(v[7], b + 7);
    }
}

__global__ __launch_bounds__(256) void up2_k4_wave(
    const float* __restrict__ x, const float* __restrict__ kw,
    float* __restrict__ out)
{
    const int H = 256, W = 256, OH = 511, OW = 511;
    int t  = threadIdx.x;                       // lane 0..63
    int ty = blockIdx.y * 4 + threadIdx.y;      // input row 0..255
    int bc = blockIdx.z;

    const float4* k4 = (const float4*)kw;       // uniform -> SGPR loads
    float4 K0 = k4[0], K1 = k4[1], K2 = k4[2], K3 = k4[3];

    const float* xp = x + (size_t)bc * (H * W);
    int rm = (ty > 0) ? ty - 1 : 0;
    int rp = (ty < H - 1) ? ty + 1 : H - 1;
    float4 m = ((const float4*)(xp + (size_t)rm * W))[t];
    float4 z = ((const float4*)(xp + (size_t)ty * W))[t];
    float4 p = ((const float4*)(xp + (size_t)rp * W))[t];
    if (ty == 0) { m.x = m.y = m.z = m.w = 0.f; }

    // halos: left = prev lane's .w, right = next lane's .x
    float mL = __shfl_up(m.w, 1), zL = __shfl_up(z.w, 1), pL = __shfl_up(p.w, 1);
    float mR = __shfl_down(m.x, 1), zR = __shfl_down(z.x, 1), pR = __shfl_down(p.x, 1);
    if (t == 0) { mL = 0.f; zL = 0.f; pL = 0.f; }
    // t==63: mR/zR/pR garbage but only feed e[7]/o[7], which lane 63 never stores.

    float e[8], o[8];
    // even out-row (2ty): rows (ty-1 -> K3, ty -> K1)
    e[0] = K3.w*mL  + K3.y*m.x + K1.w*zL  + K1.y*z.x;
    e[1] = K3.z*m.x + K3.x*m.y + K1.z*z.x + K1.x*z.y;
    e[2] = K3.w*m.x + K3.y*m.y + K1.w*z.x + K1.y*z.y;
    e[3] = K3.z*m.y + K3.x*m.z + K1.z*z.y + K1.x*z.z;
    e[4] = K3.w*m.y + K3.y*m.z + K1.w*z.y + K1.y*z.z;
    e[5] = K3.z*m.z + K3.x*m.w + K1.z*z.z + K1.x*z.w;
    e[6] = K3.w*m.z + K3.y*m.w + K1.w*z.z + K1.y*z.w;
    e[7] = K3.z*m.w + K3.x*mR  + K1.z*z.w + K1.x*zR;
    // odd out-row (2ty+1): rows (ty -> K2, ty+1 -> K0)
    o[0] = K2.w*zL  + K2.y*z.x + K0.w*pL  + K0.y*p.x;
    o[1] = K2.z*z.x + K2.x*z.y + K0.z*p.x + K0.x*p.y;
    o[2] = K2.w*z.x + K2.y*z.y + K0.w*p.x + K0.y*p.y;
    o[3] = K2.z*z.y + K2.x*z.z + K0.z*p.y + K0.x*p.z;
    o[4] = K2.w*z.y + K2.y*z.z + K0.w*p.y + K0.y*p.z;
    o[5] = K2.z*z.z + K2.x*z.w + K0.z*p.z + K0.x*p.w;
    o[6] = K2.w*z.z + K2.y*z.w + K0.w*p.z + K0.y*p.w;
    o[7] = K2.z*z.w + K2.x*zR  + K0.z*p.w + K0.x*pR;

    size_t ebase = ((size_t)bc * OH + (size_t)(2 * ty)) * OW + 8 * t;
    int mis = bc & 1;                 // plane base is odd # of floats for odd bc
    int tail = (t == 63);
    store8(out + ebase, e, mis, tail);
    if (ty < H - 1) store8(out + ebase + OW, o, mis ^ 1, tail);  // OW odd: parity flips
}

extern "C" void kernel_launch(void* const* d_in, const int* in_sizes, int n_in,
                              void* d_out, int out_size, void* d_ws, size_t ws_size,
                              hipStream_t stream) {
    const float* x = (const float*)d_in[0];
    const float* k = (const float*)d_in[1];
    float* out = (float*)d_out;

    const int H = 256, W = 256;
    int BC = in_sizes[0] / (H * W);   // 512

    dim3 block(64, 4, 1);             // one wave per input row
    dim3 grid(1, H / 4, BC);          // (1, 64, 512)
    hipLaunchKernelGGL(up2_k4_wave, grid, block, 0, stream, x, k, out);
}

// Round 5
// 198.474 us; speedup vs baseline: 2.2632x; 2.2632x over previous
//
#include <hip/hip_runtime.h>

// UpsampleUpFIRDn (up=2, 4x4 FIR). Wave-per-input-row: lane t holds float4 of
// input cols 4t..4t+3 for rows ty-1, ty, ty+1; produces output rows 2ty,2ty+1,
// cols 8t..8t+7. Halos via __shfl. Stores: plain (L2-cached) — nontemporal
// caused 2.4x write amplification (round 3). Widest aligned vector per the
// wave-uniform row-base alignment.

typedef float v2f __attribute__((ext_vector_type(2)));
typedef float v4f __attribute__((ext_vector_type(4)));

__device__ __forceinline__ void store8(float* b, const float v[8], int r, int tail)
{
    // b = row segment base (float*), r = (float index of b) & 3, wave-uniform.
    // tail: lane 63 — only v[0..6] valid (ox=504..510).
    if (r == 0) {
        *(v4f*)b = (v4f){v[0], v[1], v[2], v[3]};
        if (!tail) *(v4f*)(b + 4) = (v4f){v[4], v[5], v[6], v[7]};
        else { *(v2f*)(b + 4) = (v2f){v[4], v[5]}; b[6] = v[6]; }
    } else if (r == 1) {
        b[0] = v[0];
        *(v2f*)(b + 1) = (v2f){v[1], v[2]};
        *(v4f*)(b + 3) = (v4f){v[3], v[4], v[5], v[6]};
        if (!tail) b[7] = v[7];
    } else if (r == 2) {
        *(v2f*)b = (v2f){v[0], v[1]};
        *(v4f*)(b + 2) = (v4f){v[2], v[3], v[4], v[5]};
        if (!tail) *(v2f*)(b + 6) = (v2f){v[6], v[7]};
        else b[6] = v[6];
    } else {
        b[0] = v[0];
        *(v4f*)(b + 1) = (v4f){v[1], v[2], v[3], v[4]};
        *(v2f*)(b + 5) = (v2f){v[5], v[6]};
        if (!tail) b[7] = v[7];
    }
}

__global__ __launch_bounds__(256) void up2_k4_wave(
    const float* __restrict__ x, const float* __restrict__ kw,
    float* __restrict__ out)
{
    const int H = 256, W = 256, OH = 511, OW = 511;
    int t  = threadIdx.x;                       // lane 0..63
    int ty = blockIdx.y * 4 + threadIdx.y;      // input row 0..255
    int bc = blockIdx.z;

    const float4* k4 = (const float4*)kw;       // uniform -> SGPR loads
    float4 K0 = k4[0], K1 = k4[1], K2 = k4[2], K3 = k4[3];

    const float* xp = x + (size_t)bc * (H * W);
    int rm = (ty > 0) ? ty - 1 : 0;
    int rp = (ty < H - 1) ? ty + 1 : H - 1;
    float4 m = ((const float4*)(xp + (size_t)rm * W))[t];
    float4 z = ((const float4*)(xp + (size_t)ty * W))[t];
    float4 p = ((const float4*)(xp + (size_t)rp * W))[t];
    if (ty == 0) { m.x = m.y = m.z = m.w = 0.f; }

    // halos: left = prev lane's .w, right = next lane's .x
    float mL = __shfl_up(m.w, 1), zL = __shfl_up(z.w, 1), pL = __shfl_up(p.w, 1);
    float mR = __shfl_down(m.x, 1), zR = __shfl_down(z.x, 1), pR = __shfl_down(p.x, 1);
    if (t == 0) { mL = 0.f; zL = 0.f; pL = 0.f; }
    // t==63: mR/zR/pR garbage but only feed e[7]/o[7], which lane 63 never stores.

    float e[8], o[8];
    // even out-row (2ty): rows (ty-1 -> K3, ty -> K1)
    e[0] = K3.w*mL  + K3.y*m.x + K1.w*zL  + K1.y*z.x;
    e[1] = K3.z*m.x + K3.x*m.y + K1.z*z.x + K1.x*z.y;
    e[2] = K3.w*m.x + K3.y*m.y + K1.w*z.x + K1.y*z.y;
    e[3] = K3.z*m.y + K3.x*m.z + K1.z*z.y + K1.x*z.z;
    e[4] = K3.w*m.y + K3.y*m.z + K1.w*z.y + K1.y*z.z;
    e[5] = K3.z*m.z + K3.x*m.w + K1.z*z.z + K1.x*z.w;
    e[6] = K3.w*m.z + K3.y*m.w + K1.w*z.z + K1.y*z.w;
    e[7] = K3.z*m.w + K3.x*mR  + K1.z*z.w + K1.x*zR;
    // odd out-row (2ty+1): rows (ty -> K2, ty+1 -> K0)
    o[0] = K2.w*zL  + K2.y*z.x + K0.w*pL  + K0.y*p.x;
    o[1] = K2.z*z.x + K2.x*z.y + K0.z*p.x + K0.x*p.y;
    o[2] = K2.w*z.x + K2.y*z.y + K0.w*p.x + K0.y*p.y;
    o[3] = K2.z*z.y + K2.x*z.z + K0.z*p.y + K0.x*p.z;
    o[4] = K2.w*z.y + K2.y*z.z + K0.w*p.y + K0.y*p.z;
    o[5] = K2.z*z.z + K2.x*z.w + K0.z*p.z + K0.x*p.w;
    o[6] = K2.w*z.z + K2.y*z.w + K0.w*p.z + K0.y*p.w;
    o[7] = K2.z*z.w + K2.x*zR  + K0.z*p.w + K0.x*pR;

    size_t plane = (size_t)bc * OH * OW;
    size_t erow  = plane + (size_t)(2 * ty) * OW;
    int ra = (int)(erow & 3);          // wave-uniform alignment of even row
    int tail = (t == 63);
    store8(out + erow + 8 * t, e, ra, tail);
    if (ty < H - 1) {
        size_t orow = erow + OW;       // OW=511: alignment shifts by 3 mod 4
        store8(out + orow + 8 * t, o, (ra + 3) & 3, tail);
    }
}

extern "C" void kernel_launch(void* const* d_in, const int* in_sizes, int n_in,
                              void* d_out, int out_size, void* d_ws, size_t ws_size,
                              hipStream_t stream) {
    const float* x = (const float*)d_in[0];
    const float* k = (const float*)d_in[1];
    float* out = (float*)d_out;

    const int H = 256, W = 256;
    int BC = in_sizes[0] / (H * W);   // 512

    dim3 block(64, 4, 1);             // one wave per input row
    dim3 grid(1, H / 4, BC);          // (1, 64, 512)
    hipLaunchKernelGGL(up2_k4_wave, grid, block, 0, stream, x, k, out);
}